// Round 18
// baseline (118.376 us; speedup 1.0000x reference)
//
#include <hip/hip_runtime.h>
#include <hip/hip_bf16.h>

#define BDIM 2
#define NSEQ 2048
#define CDIM 1024
#define HNUM 16
#define DDIM 64
// softmax scale with log2(e) folded in: P = 2^(S * log2e)
#define QSCALE 0.18033688f

typedef __attribute__((ext_vector_type(4))) float f4;
typedef __attribute__((ext_vector_type(8))) short s8;

__device__ __forceinline__ unsigned short f2bf_hi(float f) {
  unsigned int u = __float_as_uint(f);
  u += 0x7fffu + ((u >> 16) & 1u);
  return (unsigned short)(u >> 16);
}
__device__ __forceinline__ unsigned int pack_bf16x2(float lo, float hi) {
  __hip_bfloat162 b2 = __float22bfloat162_rn(float2{lo, hi});
  union { __hip_bfloat162 b; unsigned int u; } c;
  c.b = b2;
  return c.u;
}
__device__ __forceinline__ float exp2_raw(float x) {
  float r;
  asm("v_exp_f32 %0, %1" : "=v"(r) : "v"(x));   // VOP1: D = 2^S0
  return r;
}
__device__ __forceinline__ void gll16(const void* g, void* l) {
  __builtin_amdgcn_global_load_lds(
      (const __attribute__((address_space(1))) unsigned int*)g,
      (__attribute__((address_space(3))) unsigned int*)l, 16, 0, 0);
}

// ============================================================
// prep: merged prepasses.
// ============================================================
__global__ __launch_bounds__(256)
void prep(const float* __restrict__ X, const float* __restrict__ Wq,
          const float* __restrict__ Wp,
          short* __restrict__ Xh, short* __restrict__ Wqh, short* __restrict__ Wph)
{
  __shared__ float T[64][65];
  const int bx = blockIdx.x;
  const int t = threadIdx.x;

  if (bx < 2048) {               // ---- split X ----
    size_t i = ((size_t)bx * 256 + t) * 8;
    f4 a = *(const f4*)(X + i), b = *(const f4*)(X + i + 4);
    s8 h;
    #pragma unroll
    for (int j = 0; j < 4; ++j) h[j] = (short)f2bf_hi(a[j]);
    #pragma unroll
    for (int j = 0; j < 4; ++j) h[4 + j] = (short)f2bf_hi(b[j]);
    *(s8*)(Xh + i) = h;
    return;
  }

  // ---- transpose + bf16 one weight tile ----
  const float* W;
  short* Th;
  int N, c0, k0;
  if (bx < 2816) {
    int b2 = bx - 2048;
    W = Wq; Th = Wqh; N = 3072;
    c0 = (b2 % 48) * 64; k0 = (b2 / 48) * 64;
  } else {
    int b2 = bx - 2816;
    W = Wp; Th = Wph; N = 1024;
    c0 = (b2 & 15) * 64; k0 = (b2 >> 4) * 64;
  }
  {
    const int r = t >> 2, c16 = (t & 3) * 16;
    const float* src = W + (size_t)(k0 + r) * N + c0 + c16;
    #pragma unroll
    for (int q = 0; q < 4; ++q) {
      f4 v = *(const f4*)(src + q * 4);
      #pragma unroll
      for (int j = 0; j < 4; ++j) T[c16 + q * 4 + j][r] = v[j];
    }
  }
  __syncthreads();
  {
    const int rr = t >> 2, k16 = (t & 3) * 16;
    s8 h0, h1;
    #pragma unroll
    for (int j = 0; j < 8; ++j) h0[j] = (short)f2bf_hi(T[rr][k16 + j]);
    #pragma unroll
    for (int j = 0; j < 8; ++j) h1[j] = (short)f2bf_hi(T[rr][k16 + 8 + j]);
    size_t o = (size_t)(c0 + rr) * 1024 + k0 + k16;
    *(s8*)(Th + o) = h0;
    *(s8*)(Th + o + 8) = h1;
  }
}

// ============================================================
// GEMM qkv (1-term bf16): C[4096][3072] = Xh @ Wqh.
// Q pre-scaled by SCALE*log2e; V written DIRECTLY transposed.
// ============================================================
__global__ __launch_bounds__(256, 3)
void gemm_qkv(const short* __restrict__ Ah_g, const short* __restrict__ Bth,
              short* __restrict__ Qh, short* __restrict__ Kh, short* __restrict__ Vt)
{
  __shared__ __align__(16) short lds[2][2][128 * 32];
  const int t = threadIdx.x, w = t >> 6, lane = t & 63;
  const int fr = lane & 15, g = lane >> 4;
  const int wr = (w >> 1) * 64, wc = (w & 1) * 64;
  const int m0 = blockIdx.y * 128, c0 = blockIdx.x * 128;

  f4 acc[4][4];
  #pragma unroll
  for (int i = 0; i < 4; ++i)
    #pragma unroll
    for (int j = 0; j < 4; ++j)
      #pragma unroll
      for (int r = 0; r < 4; ++r) acc[i][j][r] = 0.f;

  auto stage = [&](int buf, int kt) {
    const int k0 = kt * 32;
    #pragma unroll
    for (int p = 0; p < 4; ++p) {
      const int plane = p >> 1;
      const int cid = (p & 1) * 256 + t;
      const int r = cid >> 2, c = cid & 3;
      const short* gsrc = (plane == 0)
          ? Ah_g + (size_t)(m0 + r) * 1024 + k0 + c * 8
          : Bth + (size_t)(c0 + r) * 1024 + k0 + c * 8;
      gll16(gsrc, &lds[buf][plane][(p & 1) * 2048 + w * 512]);
    }
  };

  auto compute = [&](int buf) {
    const short* A_h = lds[buf][0];
    const short* B_h = lds[buf][1];
    s8 ah[4], bh[4];
    #pragma unroll
    for (int i = 0; i < 4; ++i) ah[i] = *(const s8*)&A_h[(wr + i * 16 + fr) * 32 + g * 8];
    #pragma unroll
    for (int j = 0; j < 4; ++j) bh[j] = *(const s8*)&B_h[(wc + j * 16 + fr) * 32 + g * 8];
    #pragma unroll
    for (int i = 0; i < 4; ++i)
      #pragma unroll
      for (int j = 0; j < 4; ++j)
        acc[i][j] = __builtin_amdgcn_mfma_f32_16x16x32_bf16(ah[i], bh[j], acc[i][j], 0, 0, 0);
  };

  stage(0, 0);
  __syncthreads();
  int cur = 0;
  for (int kt = 0; kt < 32; ++kt) {
    if (kt + 1 < 32) stage(cur ^ 1, kt + 1);
    compute(cur);
    __syncthreads();
    cur ^= 1;
  }

  const int ts = c0 >> 10;   // 0=Q 1=K 2=V
  const int rbase = g * 4;
  if (ts == 2) {
    #pragma unroll
    for (int i = 0; i < 4; ++i)
      #pragma unroll
      for (int j = 0; j < 4; ++j) {
        int grow = m0 + wr + i * 16 + rbase;
        int gcol = c0 + wc + j * 16 + fr;
        int b = grow >> 11, n = grow & 2047;
        int rem = gcol & 1023, hh = rem >> 6, d = rem & 63;
        short4 pv;
        pv.x = (short)f2bf_hi(acc[i][j][0]);
        pv.y = (short)f2bf_hi(acc[i][j][1]);
        pv.z = (short)f2bf_hi(acc[i][j][2]);
        pv.w = (short)f2bf_hi(acc[i][j][3]);
        *(short4*)(Vt + (((size_t)(b * 16 + hh)) * 64 + d) * 2048 + n) = pv;
      }
  } else {
    #pragma unroll
    for (int i = 0; i < 4; ++i)
      #pragma unroll
      for (int j = 0; j < 4; ++j)
        #pragma unroll
        for (int rr = 0; rr < 4; ++rr) {
          int grow = m0 + wr + i * 16 + rbase + rr;
          int gcol = c0 + wc + j * 16 + fr;
          int b = grow >> 11, n = grow & 2047;
          int rem = gcol & 1023, hh = rem >> 6, d = rem & 63;
          size_t o = (((size_t)(b * 16 + hh)) * 2048 + n) * 64 + d;
          float v = acc[i][j][rr];
          if (ts == 0) Qh[o] = (short)f2bf_hi(v * QSCALE);
          else         Kh[o] = (short)f2bf_hi(v);
        }
  }
}

// ============================================================
// Flash attention v14 = proven v11 (register-blocked 32 q/wave,
// 4 waves, K/V fragments reused across 2 q-subtiles) with pb pad
// 88->72 (conflict-profile identical) => LDS 51200 B => 3
// blocks/CU = 12 waves/CU (was 8). DS traffic 0.68x of v9 at
// restored occupancy: attacks the measured DS-throughput bound.
// ============================================================
__global__ __launch_bounds__(256, 3)
void attn(const short* __restrict__ Qh, const short* __restrict__ Kh,
          const short* __restrict__ Vt,
          short* __restrict__ AOh)
{
  __shared__ __align__(16) short kb[2][64 * 64], vb[2][64 * 64];
  __shared__ __align__(16) short pb[4][32][72];
  const int t = threadIdx.x, w = t >> 6, lane = t & 63;
  const int fr = lane & 15, g = lane >> 4;
  const int bid = blockIdx.x;
  const int swz = (bid & 7) * 64 + (bid >> 3);   // bijective: 512 % 8 == 0
  const int bh = swz >> 4, qb = swz & 15, q0 = qb * 128;
  const size_t base = (size_t)bh * 2048 * 64;

  // hoisted Q fragments: wave owns 32 q-rows (2 subtiles of 16)
  s8 qf[2][2];   // [qs][ks]
  #pragma unroll
  for (int qs = 0; qs < 2; ++qs) {
    const int qrow = q0 + w * 32 + qs * 16 + fr;
    #pragma unroll
    for (int ks = 0; ks < 2; ++ks)
      qf[qs][ks] = *(const s8*)(Qh + base + (size_t)qrow * 64 + ks * 32 + g * 8);
  }

  // bf16 1.0 fragment for l-accumulation MFMA
  s8 onesf;
  #pragma unroll
  for (int i = 0; i < 8; ++i) onesf[i] = (short)0x3F80;

  f4 oacc[2][4], lacc[2];
  #pragma unroll
  for (int qs = 0; qs < 2; ++qs) {
    #pragma unroll
    for (int dj = 0; dj < 4; ++dj)
      #pragma unroll
      for (int r = 0; r < 4; ++r) oacc[qs][dj][r] = 0.f;
    #pragma unroll
    for (int r = 0; r < 4; ++r) lacc[qs][r] = 0.f;
  }

  auto stage = [&](int buf, int kt) {
    const int kv0 = kt * 64;
    #pragma unroll
    for (int p = 0; p < 2; ++p) {
      const int cid = p * 256 + t;
      const int r = cid >> 3, csw = cid & 7, cl = csw ^ (r & 7);
      gll16(Kh + base + (size_t)(kv0 + r) * 64 + cl * 8, &kb[buf][cid * 8]);
      gll16(Vt + base + (size_t)r * 2048 + kv0 + cl * 8, &vb[buf][cid * 8]);
    }
  };

  auto body = [&](const short* kbuf, const short* vbuf) {
    // S^T = K · Q^T for both q-subtiles; each K fragment read once.
    f4 st[4][2];   // [jkv][qs]
    #pragma unroll
    for (int j = 0; j < 4; ++j)
      #pragma unroll
      for (int qs = 0; qs < 2; ++qs)
        #pragma unroll
        for (int r = 0; r < 4; ++r) st[j][qs][r] = 0.f;
    __builtin_amdgcn_s_setprio(1);
    #pragma unroll
    for (int j = 0; j < 4; ++j) {
      const int R = j * 16 + fr;
      #pragma unroll
      for (int ks = 0; ks < 2; ++ks) {
        const int co = ((ks * 4 + g) ^ (R & 7)) * 8;
        s8 khf = *(const s8*)&kbuf[R * 64 + co];
        st[j][0] = __builtin_amdgcn_mfma_f32_16x16x32_bf16(khf, qf[0][ks], st[j][0], 0, 0, 0);
        st[j][1] = __builtin_amdgcn_mfma_f32_16x16x32_bf16(khf, qf[1][ks], st[j][1], 0, 0, 0);
      }
    }
    __builtin_amdgcn_s_setprio(0);

    // p = 2^(S'), pack, write to per-wave LDS (b64)
    #pragma unroll
    for (int qs = 0; qs < 2; ++qs)
      #pragma unroll
      for (int j = 0; j < 4; ++j) {
        float p0 = exp2_raw(st[j][qs][0]);
        float p1 = exp2_raw(st[j][qs][1]);
        float p2 = exp2_raw(st[j][qs][2]);
        float p3 = exp2_raw(st[j][qs][3]);
        uint2 wv;
        wv.x = pack_bf16x2(p0, p1);
        wv.y = pack_bf16x2(p2, p3);
        *(uint2*)&pb[w][qs * 16 + fr][j * 16 + g * 4] = wv;
      }

    // PV: O += P @ V ; l += P @ 1. Each V fragment read once,
    // reused for both q-subtiles.
    __builtin_amdgcn_s_setprio(1);
    #pragma unroll
    for (int ks = 0; ks < 2; ++ks) {
      s8 pa0 = *(const s8*)&pb[w][0 * 16 + fr][ks * 32 + g * 8];
      s8 pa1 = *(const s8*)&pb[w][1 * 16 + fr][ks * 32 + g * 8];
      #pragma unroll
      for (int dj = 0; dj < 4; ++dj) {
        const int R = dj * 16 + fr;
        const int co = ((ks * 4 + g) ^ (R & 7)) * 8;
        s8 vbf = *(const s8*)&vbuf[R * 64 + co];
        oacc[0][dj] = __builtin_amdgcn_mfma_f32_16x16x32_bf16(pa0, vbf, oacc[0][dj], 0, 0, 0);
        oacc[1][dj] = __builtin_amdgcn_mfma_f32_16x16x32_bf16(pa1, vbf, oacc[1][dj], 0, 0, 0);
      }
      lacc[0] = __builtin_amdgcn_mfma_f32_16x16x32_bf16(pa0, onesf, lacc[0], 0, 0, 0);
      lacc[1] = __builtin_amdgcn_mfma_f32_16x16x32_bf16(pa1, onesf, lacc[1], 0, 0, 0);
    }
    __builtin_amdgcn_s_setprio(0);
  };

  stage(0, 0);
  for (int kt = 0; kt < 32; kt += 2) {
    __syncthreads();                       // buf0 staged; prior reads of buf1 done
    stage(1, kt + 1);                      // kt+1 <= 31 always (kt even)
    body(kb[0], vb[0]);
    __syncthreads();                       // buf1 staged; reads of buf0 done
    if (kt + 2 < 32) stage(0, kt + 2);
    body(kb[1], vb[1]);
  }

  // epilogue: oacc[qs] rows are q_local = qs*16 + g*4 + r; lacc matches.
  const int b = bh >> 4, h = bh & 15;
  #pragma unroll
  for (int qs = 0; qs < 2; ++qs) {
    float linv[4];
    #pragma unroll
    for (int r = 0; r < 4; ++r) linv[r] = 1.f / lacc[qs][r];
    #pragma unroll
    for (int dj = 0; dj < 4; ++dj)
      #pragma unroll
      for (int rr = 0; rr < 4; ++rr) {
        int n = q0 + w * 32 + qs * 16 + g * 4 + rr;
        int col = h * 64 + dj * 16 + fr;
        size_t o = ((size_t)b * 2048 + n) * 1024 + col;
        AOh[o] = (short)f2bf_hi(oacc[qs][dj][rr] * linv[rr]);
      }
  }
}

// ============================================================
// GEMM proj (1-term bf16): out[4096][1024] = AOh @ Wph + bias.
// ============================================================
__global__ __launch_bounds__(256, 2)
void gemm_proj(const short* __restrict__ Ah_g, const short* __restrict__ Bth,
               const float* __restrict__ bias, float* __restrict__ OUT)
{
  __shared__ __align__(16) short la[2][4096], lb[2][2048];
  const int t = threadIdx.x, w = t >> 6, lane = t & 63;
  const int fr = lane & 15, g = lane >> 4;
  const int wr = (w >> 1) * 64, wc = (w & 1) * 32;
  const int m0 = blockIdx.y * 128, c0 = blockIdx.x * 64;

  f4 acc[4][2];
  #pragma unroll
  for (int i = 0; i < 4; ++i)
    #pragma unroll
    for (int j = 0; j < 2; ++j)
      #pragma unroll
      for (int r = 0; r < 4; ++r) acc[i][j][r] = 0.f;

  auto stage = [&](int buf, int kt) {
    const int k0 = kt * 32;
    #pragma unroll
    for (int p = 0; p < 2; ++p) {
      const int cid = p * 256 + t;
      const int r = cid >> 2, c = cid & 3;
      gll16(Ah_g + (size_t)(m0 + r) * 1024 + k0 + c * 8, la[buf] + cid * 8);
    }
    {
      const int r = t >> 2, c = t & 3;
      gll16(Bth + (size_t)(c0 + r) * 1024 + k0 + c * 8, lb[buf] + t * 8);
    }
  };

  auto compute = [&](int buf) {
    s8 ah[4], bhf[2];
    #pragma unroll
    for (int i = 0; i < 4; ++i) ah[i] = *(const s8*)&la[buf][(wr + i * 16 + fr) * 32 + g * 8];
    #pragma unroll
    for (int j = 0; j < 2; ++j) bhf[j] = *(const s8*)&lb[buf][(wc + j * 16 + fr) * 32 + g * 8];
    #pragma unroll
    for (int i = 0; i < 4; ++i)
      #pragma unroll
      for (int j = 0; j < 2; ++j)
        acc[i][j] = __builtin_amdgcn_mfma_f32_16x16x32_bf16(ah[i], bhf[j], acc[i][j], 0, 0, 0);
  };

  stage(0, 0);
  __syncthreads();
  int cur = 0;
  for (int kt = 0; kt < 32; ++kt) {
    if (kt + 1 < 32) stage(cur ^ 1, kt + 1);
    compute(cur);
    __syncthreads();
    cur ^= 1;
  }

  const int rbase = g * 4;
  #pragma unroll
  for (int i = 0; i < 4; ++i)
    #pragma unroll
    for (int j = 0; j < 2; ++j)
      #pragma unroll
      for (int rr = 0; rr < 4; ++rr) {
        int grow = m0 + wr + i * 16 + rbase + rr;
        int gcol = c0 + wc + j * 16 + fr;
        OUT[(size_t)grow * 1024 + gcol] = acc[i][j][rr] + bias[gcol];
      }
}

// ============================================================
extern "C" void kernel_launch(void* const* d_in, const int* in_sizes, int n_in,
                              void* d_out, int out_size, void* d_ws, size_t ws_size,
                              hipStream_t stream) {
  const float* x      = (const float*)d_in[0];
  const float* w_qkv  = (const float*)d_in[1];
  const float* w_proj = (const float*)d_in[2];
  const float* b_proj = (const float*)d_in[3];
  short* ws = (short*)d_ws;

  const size_t SW = (size_t)3072 * 1024;   // Wq^T plane
  const size_t SP = (size_t)1024 * 1024;   // Wp^T plane
  const size_t SX = (size_t)4096 * 1024;   // [B,H,N,D] / [B,N,C] plane
  short* Wqh = ws;
  short* Wph = Wqh + SW;
  short* Xh  = Wph + SP;
  short* Qh  = Xh + SX;
  short* Kh  = Qh + SX;
  short* Vt  = Kh + SX;
  short* AOh = Xh;   // alias: X dead after gemm_qkv

  prep<<<3072, 256, 0, stream>>>(x, w_qkv, w_proj, Xh, Wqh, Wph);
  gemm_qkv<<<dim3(24, 32), 256, 0, stream>>>(Xh, Wqh, Qh, Kh, Vt);
  attn<<<512, 256, 0, stream>>>(Qh, Kh, Vt, AOh);
  gemm_proj<<<dim3(16, 32), 256, 0, stream>>>(AOh, Wph, b_proj, (float*)d_out);
}

// Round 20
// 111.849 us; speedup vs baseline: 1.0584x; 1.0584x over previous
//
#include <hip/hip_runtime.h>
#include <hip/hip_bf16.h>

#define BDIM 2
#define NSEQ 2048
#define CDIM 1024
#define HNUM 16
#define DDIM 64
// softmax scale with log2(e) folded in: P = 2^(S * log2e)
#define QSCALE 0.18033688f

typedef __attribute__((ext_vector_type(4))) float f4;
typedef __attribute__((ext_vector_type(8))) short s8;

__device__ __forceinline__ unsigned short f2bf_hi(float f) {
  unsigned int u = __float_as_uint(f);
  u += 0x7fffu + ((u >> 16) & 1u);
  return (unsigned short)(u >> 16);
}
__device__ __forceinline__ unsigned int pack_bf16x2(float lo, float hi) {
  __hip_bfloat162 b2 = __float22bfloat162_rn(float2{lo, hi});
  union { __hip_bfloat162 b; unsigned int u; } c;
  c.b = b2;
  return c.u;
}
__device__ __forceinline__ float exp2_raw(float x) {
  float r;
  asm("v_exp_f32 %0, %1" : "=v"(r) : "v"(x));   // VOP1: D = 2^S0
  return r;
}
__device__ __forceinline__ void gll16(const void* g, void* l) {
  __builtin_amdgcn_global_load_lds(
      (const __attribute__((address_space(1))) unsigned int*)g,
      (__attribute__((address_space(3))) unsigned int*)l, 16, 0, 0);
}

// ============================================================
// prep: merged prepasses.
// ============================================================
__global__ __launch_bounds__(256)
void prep(const float* __restrict__ X, const float* __restrict__ Wq,
          const float* __restrict__ Wp,
          short* __restrict__ Xh, short* __restrict__ Wqh, short* __restrict__ Wph)
{
  __shared__ float T[64][65];
  const int bx = blockIdx.x;
  const int t = threadIdx.x;

  if (bx < 2048) {               // ---- split X ----
    size_t i = ((size_t)bx * 256 + t) * 8;
    f4 a = *(const f4*)(X + i), b = *(const f4*)(X + i + 4);
    s8 h;
    #pragma unroll
    for (int j = 0; j < 4; ++j) h[j] = (short)f2bf_hi(a[j]);
    #pragma unroll
    for (int j = 0; j < 4; ++j) h[4 + j] = (short)f2bf_hi(b[j]);
    *(s8*)(Xh + i) = h;
    return;
  }

  // ---- transpose + bf16 one weight tile ----
  const float* W;
  short* Th;
  int N, c0, k0;
  if (bx < 2816) {
    int b2 = bx - 2048;
    W = Wq; Th = Wqh; N = 3072;
    c0 = (b2 % 48) * 64; k0 = (b2 / 48) * 64;
  } else {
    int b2 = bx - 2816;
    W = Wp; Th = Wph; N = 1024;
    c0 = (b2 & 15) * 64; k0 = (b2 >> 4) * 64;
  }
  {
    const int r = t >> 2, c16 = (t & 3) * 16;
    const float* src = W + (size_t)(k0 + r) * N + c0 + c16;
    #pragma unroll
    for (int q = 0; q < 4; ++q) {
      f4 v = *(const f4*)(src + q * 4);
      #pragma unroll
      for (int j = 0; j < 4; ++j) T[c16 + q * 4 + j][r] = v[j];
    }
  }
  __syncthreads();
  {
    const int rr = t >> 2, k16 = (t & 3) * 16;
    s8 h0, h1;
    #pragma unroll
    for (int j = 0; j < 8; ++j) h0[j] = (short)f2bf_hi(T[rr][k16 + j]);
    #pragma unroll
    for (int j = 0; j < 8; ++j) h1[j] = (short)f2bf_hi(T[rr][k16 + 8 + j]);
    size_t o = (size_t)(c0 + rr) * 1024 + k0 + k16;
    *(s8*)(Th + o) = h0;
    *(s8*)(Th + o + 8) = h1;
  }
}

// ============================================================
// GEMM qkv (1-term bf16): C[4096][3072] = Xh @ Wqh.
// Q pre-scaled by SCALE*log2e; V written DIRECTLY transposed.
// ============================================================
__global__ __launch_bounds__(256, 3)
void gemm_qkv(const short* __restrict__ Ah_g, const short* __restrict__ Bth,
              short* __restrict__ Qh, short* __restrict__ Kh, short* __restrict__ Vt)
{
  __shared__ __align__(16) short lds[2][2][128 * 32];
  const int t = threadIdx.x, w = t >> 6, lane = t & 63;
  const int fr = lane & 15, g = lane >> 4;
  const int wr = (w >> 1) * 64, wc = (w & 1) * 64;
  const int m0 = blockIdx.y * 128, c0 = blockIdx.x * 128;

  f4 acc[4][4];
  #pragma unroll
  for (int i = 0; i < 4; ++i)
    #pragma unroll
    for (int j = 0; j < 4; ++j)
      #pragma unroll
      for (int r = 0; r < 4; ++r) acc[i][j][r] = 0.f;

  auto stage = [&](int buf, int kt) {
    const int k0 = kt * 32;
    #pragma unroll
    for (int p = 0; p < 4; ++p) {
      const int plane = p >> 1;
      const int cid = (p & 1) * 256 + t;
      const int r = cid >> 2, c = cid & 3;
      const short* gsrc = (plane == 0)
          ? Ah_g + (size_t)(m0 + r) * 1024 + k0 + c * 8
          : Bth + (size_t)(c0 + r) * 1024 + k0 + c * 8;
      gll16(gsrc, &lds[buf][plane][(p & 1) * 2048 + w * 512]);
    }
  };

  auto compute = [&](int buf) {
    const short* A_h = lds[buf][0];
    const short* B_h = lds[buf][1];
    s8 ah[4], bh[4];
    #pragma unroll
    for (int i = 0; i < 4; ++i) ah[i] = *(const s8*)&A_h[(wr + i * 16 + fr) * 32 + g * 8];
    #pragma unroll
    for (int j = 0; j < 4; ++j) bh[j] = *(const s8*)&B_h[(wc + j * 16 + fr) * 32 + g * 8];
    #pragma unroll
    for (int i = 0; i < 4; ++i)
      #pragma unroll
      for (int j = 0; j < 4; ++j)
        acc[i][j] = __builtin_amdgcn_mfma_f32_16x16x32_bf16(ah[i], bh[j], acc[i][j], 0, 0, 0);
  };

  stage(0, 0);
  __syncthreads();
  int cur = 0;
  for (int kt = 0; kt < 32; ++kt) {
    if (kt + 1 < 32) stage(cur ^ 1, kt + 1);
    compute(cur);
    __syncthreads();
    cur ^= 1;
  }

  const int ts = c0 >> 10;   // 0=Q 1=K 2=V
  const int rbase = g * 4;
  if (ts == 2) {
    #pragma unroll
    for (int i = 0; i < 4; ++i)
      #pragma unroll
      for (int j = 0; j < 4; ++j) {
        int grow = m0 + wr + i * 16 + rbase;
        int gcol = c0 + wc + j * 16 + fr;
        int b = grow >> 11, n = grow & 2047;
        int rem = gcol & 1023, hh = rem >> 6, d = rem & 63;
        short4 pv;
        pv.x = (short)f2bf_hi(acc[i][j][0]);
        pv.y = (short)f2bf_hi(acc[i][j][1]);
        pv.z = (short)f2bf_hi(acc[i][j][2]);
        pv.w = (short)f2bf_hi(acc[i][j][3]);
        *(short4*)(Vt + (((size_t)(b * 16 + hh)) * 64 + d) * 2048 + n) = pv;
      }
  } else {
    #pragma unroll
    for (int i = 0; i < 4; ++i)
      #pragma unroll
      for (int j = 0; j < 4; ++j)
        #pragma unroll
        for (int rr = 0; rr < 4; ++rr) {
          int grow = m0 + wr + i * 16 + rbase + rr;
          int gcol = c0 + wc + j * 16 + fr;
          int b = grow >> 11, n = grow & 2047;
          int rem = gcol & 1023, hh = rem >> 6, d = rem & 63;
          size_t o = (((size_t)(b * 16 + hh)) * 2048 + n) * 64 + d;
          float v = acc[i][j][rr];
          if (ts == 0) Qh[o] = (short)f2bf_hi(v * QSCALE);
          else         Kh[o] = (short)f2bf_hi(v);
        }
  }
}

// ============================================================
// Flash attention v10 (proven, round 13): cross-tile phase
// overlap, MFMA l-sums, exp2-folded scale, setprio, dbuf.
// ============================================================
__global__ __launch_bounds__(512, 2)
void attn(const short* __restrict__ Qh, const short* __restrict__ Kh,
          const short* __restrict__ Vt,
          short* __restrict__ AOh)
{
  __shared__ __align__(16) short kb[2][64 * 64], vb[2][64 * 64];
  __shared__ __align__(16) short pb[8][16][88];
  const int t = threadIdx.x, w = t >> 6, lane = t & 63;
  const int fr = lane & 15, g = lane >> 4;
  const int bid = blockIdx.x;
  const int swz = (bid & 7) * 64 + (bid >> 3);   // bijective: 512 % 8 == 0
  const int bh = swz >> 4, qb = swz & 15, q0 = qb * 128;
  const size_t base = (size_t)bh * 2048 * 64;

  // hoisted Q fragments (Q pre-scaled by SCALE*log2e)
  s8 qf[2];
  {
    const int qrow = q0 + w * 16 + fr;
    #pragma unroll
    for (int ks = 0; ks < 2; ++ks)
      qf[ks] = *(const s8*)(Qh + base + (size_t)qrow * 64 + ks * 32 + g * 8);
  }

  // bf16 1.0 fragment for l-accumulation MFMA
  s8 onesf;
  #pragma unroll
  for (int i = 0; i < 8; ++i) onesf[i] = (short)0x3F80;

  f4 oacc[4], lacc;
  #pragma unroll
  for (int dj = 0; dj < 4; ++dj)
    #pragma unroll
    for (int r = 0; r < 4; ++r) oacc[dj][r] = 0.f;
  #pragma unroll
  for (int r = 0; r < 4; ++r) lacc[r] = 0.f;

  auto stage = [&](int buf, int kt) {
    const int kv0 = kt * 64;
    const int r = t >> 3, csw = t & 7, cl = csw ^ (r & 7);
    gll16(Kh + base + (size_t)(kv0 + r) * 64 + cl * 8, &kb[buf][t * 8]);
    gll16(Vt + base + (size_t)r * 2048 + kv0 + cl * 8, &vb[buf][t * 8]);
  };

  // QK(kt) + optional PV(kt-1), then exp/pack into pb.
  auto phase = [&](const short* kbuf, const short* vbuf, int do_pv) {
    s8 pa0, pa1;
    if (do_pv) {
      pa0 = *(const s8*)&pb[w][fr][0 * 32 + g * 8];
      pa1 = *(const s8*)&pb[w][fr][1 * 32 + g * 8];
    }
    f4 st[4];
    #pragma unroll
    for (int j = 0; j < 4; ++j)
      #pragma unroll
      for (int r = 0; r < 4; ++r) st[j][r] = 0.f;

    __builtin_amdgcn_s_setprio(1);
    #pragma unroll
    for (int j = 0; j < 4; ++j) {
      const int R = j * 16 + fr;
      #pragma unroll
      for (int ks = 0; ks < 2; ++ks) {
        const int co = ((ks * 4 + g) ^ (R & 7)) * 8;
        s8 khf = *(const s8*)&kbuf[R * 64 + co];
        st[j] = __builtin_amdgcn_mfma_f32_16x16x32_bf16(khf, qf[ks], st[j], 0, 0, 0);
      }
    }
    if (do_pv) {
      #pragma unroll
      for (int dj = 0; dj < 4; ++dj) {
        const int R = dj * 16 + fr;
        const int co0 = ((0 + g) ^ (R & 7)) * 8;
        s8 vbf = *(const s8*)&vbuf[R * 64 + co0];
        oacc[dj] = __builtin_amdgcn_mfma_f32_16x16x32_bf16(pa0, vbf, oacc[dj], 0, 0, 0);
      }
      lacc = __builtin_amdgcn_mfma_f32_16x16x32_bf16(pa0, onesf, lacc, 0, 0, 0);
      #pragma unroll
      for (int dj = 0; dj < 4; ++dj) {
        const int R = dj * 16 + fr;
        const int co1 = ((4 + g) ^ (R & 7)) * 8;
        s8 vbf = *(const s8*)&vbuf[R * 64 + co1];
        oacc[dj] = __builtin_amdgcn_mfma_f32_16x16x32_bf16(pa1, vbf, oacc[dj], 0, 0, 0);
      }
      lacc = __builtin_amdgcn_mfma_f32_16x16x32_bf16(pa1, onesf, lacc, 0, 0, 0);
    }
    __builtin_amdgcn_s_setprio(0);

    // exp/pack P(kt) -> pb (overwrites the slot pa was read from)
    #pragma unroll
    for (int j = 0; j < 4; ++j) {
      float p0 = exp2_raw(st[j][0]);
      float p1 = exp2_raw(st[j][1]);
      float p2 = exp2_raw(st[j][2]);
      float p3 = exp2_raw(st[j][3]);
      uint2 wv;
      wv.x = pack_bf16x2(p0, p1);
      wv.y = pack_bf16x2(p2, p3);
      *(uint2*)&pb[w][fr][j * 16 + g * 4] = wv;
    }
  };

  stage(0, 0);
  __syncthreads();                 // buf0 ready
  phase(kb[0], vb[0], 0);          // Q(0) only
  __syncthreads();
  stage(1, 1);
  for (int kt = 1; kt < 32; ++kt) {
    const int cur = kt & 1;
    __syncthreads();               // S(kt) drained: buf[cur] ready
    phase(kb[cur], vb[cur ^ 1], 1);  // QK(kt) + PV(kt-1)
    __syncthreads();               // all waves done reading vb[cur^1], kb[cur]
    if (kt < 31) stage(cur ^ 1, kt + 1);
  }
  // tail: PV(31) from pb + vb[1]
  {
    s8 pa0 = *(const s8*)&pb[w][fr][0 * 32 + g * 8];
    s8 pa1 = *(const s8*)&pb[w][fr][1 * 32 + g * 8];
    const short* vbuf = vb[1];
    __builtin_amdgcn_s_setprio(1);
    #pragma unroll
    for (int dj = 0; dj < 4; ++dj) {
      const int R = dj * 16 + fr;
      const int co0 = ((0 + g) ^ (R & 7)) * 8;
      s8 vbf = *(const s8*)&vbuf[R * 64 + co0];
      oacc[dj] = __builtin_amdgcn_mfma_f32_16x16x32_bf16(pa0, vbf, oacc[dj], 0, 0, 0);
    }
    lacc = __builtin_amdgcn_mfma_f32_16x16x32_bf16(pa0, onesf, lacc, 0, 0, 0);
    #pragma unroll
    for (int dj = 0; dj < 4; ++dj) {
      const int R = dj * 16 + fr;
      const int co1 = ((4 + g) ^ (R & 7)) * 8;
      s8 vbf = *(const s8*)&vbuf[R * 64 + co1];
      oacc[dj] = __builtin_amdgcn_mfma_f32_16x16x32_bf16(pa1, vbf, oacc[dj], 0, 0, 0);
    }
    lacc = __builtin_amdgcn_mfma_f32_16x16x32_bf16(pa1, onesf, lacc, 0, 0, 0);
    __builtin_amdgcn_s_setprio(0);
  }

  // epilogue: oacc rows are q_local = g*4+r; lacc[r] = l[q=g*4+r] (same lane).
  const int b = bh >> 4, h = bh & 15;
  float linv[4];
  #pragma unroll
  for (int r = 0; r < 4; ++r) linv[r] = 1.f / lacc[r];
  #pragma unroll
  for (int dj = 0; dj < 4; ++dj)
    #pragma unroll
    for (int rr = 0; rr < 4; ++rr) {
      int n = q0 + w * 16 + g * 4 + rr;
      int col = h * 64 + dj * 16 + fr;
      size_t o = ((size_t)b * 2048 + n) * 1024 + col;
      AOh[o] = (short)f2bf_hi(oacc[dj][rr] * linv[rr]);
    }
}

// ============================================================
// GEMM proj (1-term bf16): out[4096][1024] = AOh @ Wph + bias.
// BK=64 (16 steps, 16 MFMA/wave/step), XOR-8 chunk swizzle
// (proven attn pattern) to kill the 128B-stride conflict.
// LDS 48KB -> 3 blocks/CU.
// ============================================================
__global__ __launch_bounds__(256, 3)
void gemm_proj(const short* __restrict__ Ah_g, const short* __restrict__ Bth,
               const float* __restrict__ bias, float* __restrict__ OUT)
{
  __shared__ __align__(16) short la[2][128 * 64], lb[2][64 * 64];
  const int t = threadIdx.x, w = t >> 6, lane = t & 63;
  const int fr = lane & 15, g = lane >> 4;
  const int wr = (w >> 1) * 64, wc = (w & 1) * 32;
  const int m0 = blockIdx.y * 128, c0 = blockIdx.x * 64;

  f4 acc[4][2];
  #pragma unroll
  for (int i = 0; i < 4; ++i)
    #pragma unroll
    for (int j = 0; j < 2; ++j)
      #pragma unroll
      for (int r = 0; r < 4; ++r) acc[i][j][r] = 0.f;

  auto stage = [&](int buf, int kt) {
    const int k0 = kt * 64;
    #pragma unroll
    for (int p = 0; p < 4; ++p) {          // A: 1024 chunks, XOR-8 swizzled
      const int cid = p * 256 + t;
      const int r = cid >> 3, csw = cid & 7, cl = csw ^ (r & 7);
      gll16(Ah_g + (size_t)(m0 + r) * 1024 + k0 + cl * 8, la[buf] + cid * 8);
    }
    #pragma unroll
    for (int p = 0; p < 2; ++p) {          // B: 512 chunks, XOR-8 swizzled
      const int cid = p * 256 + t;
      const int r = cid >> 3, csw = cid & 7, cl = csw ^ (r & 7);
      gll16(Bth + (size_t)(c0 + r) * 1024 + k0 + cl * 8, lb[buf] + cid * 8);
    }
  };

  auto compute = [&](int buf) {
    #pragma unroll
    for (int ks = 0; ks < 2; ++ks) {
      s8 ah[4], bhf[2];
      #pragma unroll
      for (int i = 0; i < 4; ++i) {
        const int R = wr + i * 16 + fr;
        const int co = ((ks * 4 + g) ^ (R & 7)) * 8;
        ah[i] = *(const s8*)&la[buf][R * 64 + co];
      }
      #pragma unroll
      for (int j = 0; j < 2; ++j) {
        const int R = wc + j * 16 + fr;
        const int co = ((ks * 4 + g) ^ (R & 7)) * 8;
        bhf[j] = *(const s8*)&lb[buf][R * 64 + co];
      }
      #pragma unroll
      for (int i = 0; i < 4; ++i)
        #pragma unroll
        for (int j = 0; j < 2; ++j)
          acc[i][j] = __builtin_amdgcn_mfma_f32_16x16x32_bf16(ah[i], bhf[j], acc[i][j], 0, 0, 0);
    }
  };

  stage(0, 0);
  __syncthreads();
  int cur = 0;
  for (int kt = 0; kt < 16; ++kt) {
    if (kt + 1 < 16) stage(cur ^ 1, kt + 1);
    compute(cur);
    __syncthreads();
    cur ^= 1;
  }

  const int rbase = g * 4;
  #pragma unroll
  for (int i = 0; i < 4; ++i)
    #pragma unroll
    for (int j = 0; j < 2; ++j)
      #pragma unroll
      for (int rr = 0; rr < 4; ++rr) {
        int grow = m0 + wr + i * 16 + rbase + rr;
        int gcol = c0 + wc + j * 16 + fr;
        OUT[(size_t)grow * 1024 + gcol] = acc[i][j][rr] + bias[gcol];
      }
}

// ============================================================
extern "C" void kernel_launch(void* const* d_in, const int* in_sizes, int n_in,
                              void* d_out, int out_size, void* d_ws, size_t ws_size,
                              hipStream_t stream) {
  const float* x      = (const float*)d_in[0];
  const float* w_qkv  = (const float*)d_in[1];
  const float* w_proj = (const float*)d_in[2];
  const float* b_proj = (const float*)d_in[3];
  short* ws = (short*)d_ws;

  const size_t SW = (size_t)3072 * 1024;   // Wq^T plane
  const size_t SP = (size_t)1024 * 1024;   // Wp^T plane
  const size_t SX = (size_t)4096 * 1024;   // [B,H,N,D] / [B,N,C] plane
  short* Wqh = ws;
  short* Wph = Wqh + SW;
  short* Xh  = Wph + SP;
  short* Qh  = Xh + SX;
  short* Kh  = Qh + SX;
  short* Vt  = Kh + SX;
  short* AOh = Xh;   // alias: X dead after gemm_qkv

  prep<<<3072, 256, 0, stream>>>(x, w_qkv, w_proj, Xh, Wqh, Wph);
  gemm_qkv<<<dim3(24, 32), 256, 0, stream>>>(Xh, Wqh, Qh, Kh, Vt);
  attn<<<512, 512, 0, stream>>>(Qh, Kh, Vt, AOh);
  gemm_proj<<<dim3(16, 32), 256, 0, stream>>>(AOh, Wph, b_proj, (float*)d_out);
}